// Round 12
// baseline (57.857 us; speedup 1.0000x reference)
//
#include <hip/hip_runtime.h>
#include <cstddef>
#include <cstdint>

#define NROWS  200000
#define CIN    32
#define COUT   64
#define KV     27
#define NWAVES (NROWS / 64)   // 3125

typedef __attribute__((ext_vector_type(8))) short  short8;
typedef __attribute__((ext_vector_type(4))) float  f32x4;

// RNE float -> bf16 (inputs finite)
__device__ __forceinline__ unsigned short f2bf(float x) {
  unsigned u = __builtin_bit_cast(unsigned, x);
  u += 0x7FFFu + ((u >> 16) & 1u);
  return (unsigned short)(u >> 16);
}

// Pack weight [27][32][64] f32 -> bf16 B-fragments, mfma_16x16x32 B layout:
// wsB[(k*4+t)*64 + lane][f] = W[k][(lane>>4)*8+f][t*16+(lane&15)]
__global__ void prep_weight_kernel(const float* __restrict__ w,
                                   short8* __restrict__ wsB) {
  int tid = blockIdx.x * blockDim.x + threadIdx.x;   // 27*4*64 = 6912
  if (tid >= KV * 4 * 64) return;
  int lane = tid & 63;
  int t    = (tid >> 6) & 3;
  int k    = tid >> 8;
  int col  = t * 16 + (lane & 15);
  int kin0 = (lane >> 4) * 8;
  short8 v;
#pragma unroll
  for (int f = 0; f < 8; ++f)
    v[f] = (short)f2bf(w[((size_t)k * CIN + kin0 + f) * COUT + col]);
  wsB[tid] = v;
}

// feats f32 [N][32] -> bf16 [N+1][32]; row N (pad) = zeros.
__global__ void prep_feats_kernel(const float* __restrict__ feats,
                                  short8* __restrict__ fb) {
  int i = blockIdx.x * blockDim.x + threadIdx.x;
  const int total8 = (NROWS + 1) * CIN / 8;          // 800004
  if (i >= total8) return;
  short8 v = {0, 0, 0, 0, 0, 0, 0, 0};
  if (i < NROWS * CIN / 8) {
    const f32x4* p = (const f32x4*)feats + (size_t)i * 2;
    f32x4 a = p[0], b = p[1];
#pragma unroll
    for (int f = 0; f < 4; ++f) {
      v[f]     = (short)f2bf(a[f]);
      v[4 + f] = (short)f2bf(b[f]);
    }
  }
  fb[i] = v;
}

#define MFMA4(AF, BF)                                                          \
  _Pragma("unroll")                                                            \
  for (int m = 0; m < 4; ++m) {                                                \
    acc[m][0] = __builtin_amdgcn_mfma_f32_16x16x32_bf16(AF[m], BF[0], acc[m][0], 0, 0, 0); \
    acc[m][1] = __builtin_amdgcn_mfma_f32_16x16x32_bf16(AF[m], BF[1], acc[m][1], 0, 0, 0); \
    acc[m][2] = __builtin_amdgcn_mfma_f32_16x16x32_bf16(AF[m], BF[2], acc[m][2], 0, 0, 0); \
    acc[m][3] = __builtin_amdgcn_mfma_f32_16x16x32_bf16(AF[m], BF[3], acc[m][3], 0, 0, 0); \
  }

// Main: R5 champion skeleton (Mw=4, idx-LDS, 256-thr blocks, no loop
// barriers) + manual unroll-2 register double-buffer with sched_barrier(0)
// fences. Each body issues B(k+1)+gather(k+1) BEFORE the MFMA cluster of k;
// both MFMA operands were issued one full body earlier, so the auto-waitcnt
// is vmcnt(8): 8 loads (4 B + 4 gathers) stay in flight across every MFMA
// cluster -> per-wave MLP depth 2 (prior rounds showed the compiler alone
// never keeps gathers in flight across MFMAs). No register rotates (R3's
// failure mode): af/ag and bfA/bfB swap ROLES via the 2x unroll.
__global__ __launch_bounds__(256, 3)
void spconv_mfma_kernel(const unsigned short* __restrict__ featsbf,
                        const short8* __restrict__ wsB,
                        const float* __restrict__ bias,
                        const int* __restrict__ in_idx,
                        float* __restrict__ out) {
  __shared__ int sIdx[4][KV][64];                    // 27,648 B

  const int tid  = threadIdx.x;
  const int lane = tid & 63;
  const int w    = tid >> 6;
  const int wid  = (int)blockIdx.x * 4 + w;
  if (wid >= NWAVES) return;                         // no barriers below
  const int row0 = wid << 6;

  // ---- stage this wave's idx block into LDS (per-wave region) ----
  {
    int tmp[KV];
#pragma unroll
    for (int k = 0; k < KV; ++k)
      tmp[k] = in_idx[(size_t)k * NROWS + row0 + lane];
#pragma unroll
    for (int k = 0; k < KV; ++k)
      sIdx[w][k][lane] = tmp[k];
  }

  const int c16  = lane & 15;
  const int kg   = lane >> 4;
  const int koff = kg * 8;

  f32x4 acc[4][4];                                   // [m][t]
#pragma unroll
  for (int t = 0; t < 4; ++t) {
    float bv = bias[t * 16 + c16];
    f32x4 bvv = {bv, bv, bv, bv};
#pragma unroll
    for (int m = 0; m < 4; ++m) acc[m][t] = bvv;
  }

  const short8* bp = wsB + lane;

  // ---- prologue: B(0), gather(0) ----
  short8 af[4], ag[4], bfA[4], bfB[4];
  {
    int idx0[4];
#pragma unroll
    for (int m = 0; m < 4; ++m) idx0[m] = sIdx[w][0][m * 16 + c16];
#pragma unroll
    for (int t = 0; t < 4; ++t) bfA[t] = bp[t * 64];
#pragma unroll
    for (int m = 0; m < 4; ++m)
      af[m] = *(const short8*)(featsbf + (size_t)idx0[m] * CIN + koff);
  }

#pragma unroll 1
  for (int k = 0; k < KV - 1; k += 2) {              // k = 0,2,...,24
    // ---- body A: prefetch (k+1), compute k ----
    {
      int idxn[4];
#pragma unroll
      for (int m = 0; m < 4; ++m) idxn[m] = sIdx[w][k + 1][m * 16 + c16];
#pragma unroll
      for (int t = 0; t < 4; ++t) bfB[t] = bp[((k + 1) * 4 + t) * 64];
#pragma unroll
      for (int m = 0; m < 4; ++m)
        ag[m] = *(const short8*)(featsbf + (size_t)idxn[m] * CIN + koff);
    }
    __builtin_amdgcn_sched_barrier(0);
    MFMA4(af, bfA)
    __builtin_amdgcn_sched_barrier(0);

    // ---- body B: prefetch (k+2), compute k+1 ----
    {
      const int k2 = k + 2;                          // <= 26, always valid
      int idxn[4];
#pragma unroll
      for (int m = 0; m < 4; ++m) idxn[m] = sIdx[w][k2][m * 16 + c16];
#pragma unroll
      for (int t = 0; t < 4; ++t) bfA[t] = bp[(k2 * 4 + t) * 64];
#pragma unroll
      for (int m = 0; m < 4; ++m)
        af[m] = *(const short8*)(featsbf + (size_t)idxn[m] * CIN + koff);
    }
    __builtin_amdgcn_sched_barrier(0);
    MFMA4(ag, bfB)
    __builtin_amdgcn_sched_barrier(0);
  }

  // ---- tail: k = 26 (af/bfA hold it) ----
  MFMA4(af, bfA)

  // D layout: col = t*16 + (lane&15), row = (lane>>4)*4 + r
#pragma unroll
  for (int m = 0; m < 4; ++m)
#pragma unroll
    for (int t = 0; t < 4; ++t)
#pragma unroll
      for (int r = 0; r < 4; ++r)
        out[(size_t)(row0 + m * 16 + kg * 4 + r) * COUT + t * 16 + c16] = acc[m][t][r];
}

// Correct-but-slow fallback if ws is tiny (shouldn't happen).
__global__ void spconv_naive_kernel(const float* __restrict__ feats,
                                    const float* __restrict__ w,
                                    const float* __restrict__ bias,
                                    const int* __restrict__ in_idx,
                                    float* __restrict__ out) {
  int gid = blockIdx.x * blockDim.x + threadIdx.x;
  if (gid >= NROWS * COUT) return;
  int row = gid / COUT, co = gid % COUT;
  float acc = bias[co];
  for (int k = 0; k < KV; ++k) {
    int idx = in_idx[(size_t)k * NROWS + row];
    if (idx < NROWS) {
      const float* fr = feats + (size_t)idx * CIN;
      const float* wk = w + (size_t)k * CIN * COUT + co;
#pragma unroll
      for (int c = 0; c < CIN; ++c) acc += fr[c] * wk[(size_t)c * COUT];
    }
  }
  out[gid] = acc;
}

extern "C" void kernel_launch(void* const* d_in, const int* in_sizes, int n_in,
                              void* d_out, int out_size, void* d_ws, size_t ws_size,
                              hipStream_t stream) {
  const float* feats  = (const float*)d_in[0];
  const float* weight = (const float*)d_in[1];
  const float* bias   = (const float*)d_in[2];
  const int*   in_idx = (const int*)d_in[3];
  float*       out    = (float*)d_out;

  const size_t wsB_bytes = (size_t)KV * 4 * 64 * 16;        // 110592
  const size_t fb_bytes  = (size_t)(NROWS + 1) * CIN * 2;   // 12800064
  short8*         wsB     = (short8*)d_ws;
  unsigned short* featsbf = (unsigned short*)((char*)d_ws + wsB_bytes);

  if (ws_size >= wsB_bytes + fb_bytes) {
    prep_weight_kernel<<<27, 256, 0, stream>>>(weight, wsB);
    prep_feats_kernel<<<((NROWS + 1) * CIN / 8 + 255) / 256, 256, 0, stream>>>(
        feats, (short8*)featsbf);
    const int blocks = (NWAVES + 3) / 4;                     // 782
    spconv_mfma_kernel<<<blocks, 256, 0, stream>>>(
        featsbf, wsB, bias, in_idx, out);
  } else {
    spconv_naive_kernel<<<(NROWS * COUT + 255) / 256, 256, 0, stream>>>(
        feats, weight, bias, in_idx, out);
  }
}